// Round 14
// baseline (216.422 us; speedup 1.0000x reference)
//
#include <hip/hip_runtime.h>

// ---------------------------------------------------------------------------
// GCN encoder: out = GCNConv2( relu(GCNConv1(x)) )
// R13: GEMM2 fused into gather1 (per-block 16x128 agg tile -> LDS -> MFMA
// -> h2 fp16), 16-edge unroll in the fused gather. agg1 buffer eliminated.
// Prep chain (hist2convW/wavescan/basescan/scatter2/csrbuild) = R12.
// GEMM1 = R7 async-LDS fp16 MFMA. gather2 = R9 clamped 8-edge rounds.
// ---------------------------------------------------------------------------

typedef __attribute__((ext_vector_type(4))) float floatx4;
typedef _Float16 __attribute__((ext_vector_type(8))) half8v;

#define BUCK_SH 6
#define BUCK    64           // dsts per bucket
#define NBLK    256          // blocks for hist2/scatter2

#define AS1(p) ((const __attribute__((address_space(1))) void*)(p))
#define AS3(p) ((__attribute__((address_space(3))) void*)(p))

__device__ __forceinline__ int edge_id(const int* __restrict__ ei, int is64, long long pos) {
    return is64 ? ei[2 * pos] : ei[(int)pos];
}

// per-block is64 detection: int64 node ids (<2^31) => odd dwords all zero.
__device__ __forceinline__ int detect_is64(const int* __restrict__ ei) {
    __shared__ int nz;
    if (threadIdx.x == 0) nz = 0;
    __syncthreads();
    if (threadIdx.x < 256 && ei[2 * threadIdx.x + 1] != 0) atomicOr(&nz, 1);
    __syncthreads();
    return (nz == 0) ? 1 : 0;
}

__device__ __forceinline__ void convW_one(const float* W, _Float16* Wt, int K, int Nc, int idx) {
    if (idx >= K * Nc) return;
    int k = idx / Nc, n = idx % Nc;
    Wt[(long long)n * K + k] = (_Float16)W[idx];
}

// ---- fused: per-block bucket histogram + weight conversion -----------------
__global__ void __launch_bounds__(256)
hist2convW_kernel(const int* __restrict__ ei, int* __restrict__ hist2,
                  int E, int NB, int chunk,
                  const float* __restrict__ W1, _Float16* __restrict__ W1t,
                  const float* __restrict__ W2, _Float16* __restrict__ W2t) {
    __shared__ int h[1024];
    const int t = threadIdx.x;
    const int is64 = detect_is64(ei);
    for (int i = t; i < NB; i += 256) h[i] = 0;
    __syncthreads();
    const int lo = blockIdx.x * chunk;
    const int hi = min(E, lo + chunk);
    for (int e = lo + t; e < hi; e += 256) {
        int d = edge_id(ei, is64, (long long)E + e);
        atomicAdd(&h[d >> BUCK_SH], 1);
    }
    __syncthreads();
    for (int i = t; i < NB; i += 256) hist2[(long long)blockIdx.x * NB + i] = h[i];
    {
        int gtid = blockIdx.x * 256 + t;
        convW_one(W1, W1t, 256, 128, gtid);
        int g2 = gtid - 256 * 128;
        if (g2 >= 0) convW_one(W2, W2t, 128, 64, g2);
    }
}

// ---- wavescan: one wave per bucket, shuffle-scan over 256 block counts -----
__global__ void __launch_bounds__(256)
wavescan_kernel(const int* __restrict__ hist2, int* __restrict__ start2t,
                int* __restrict__ colsum, int NB) {
    const int wid  = (blockIdx.x * 256 + threadIdx.x) >> 6;
    const int lane = threadIdx.x & 63;
    if (wid >= NB) return;
    int carry = 0;
    for (int c = 0; c < NBLK; c += 64) {
        int v = hist2[(long long)(c + lane) * NB + wid];
        int incl = v;
#pragma unroll
        for (int s = 1; s < 64; s <<= 1) {
            int u = __shfl_up(incl, s, 64);
            if (lane >= s) incl += u;
        }
        start2t[(long long)wid * NBLK + c + lane] = carry + incl - v;
        carry += __shfl(incl, 63, 64);
    }
    if (lane == 0) colsum[wid] = carry;
}

// ---- tiny single-block exclusive scan of colsum -> bbase[NB+1] -------------
__global__ void __launch_bounds__(1024)
basescan_kernel(const int* __restrict__ colsum, int* __restrict__ bbase, int NB, int E) {
    __shared__ int sm[1024];
    const int t = threadIdx.x;
    int v = (t < NB) ? colsum[t] : 0;
    sm[t] = v;
    __syncthreads();
    for (int s = 1; s < 1024; s <<= 1) {
        int u = (t >= s) ? sm[t - s] : 0;
        __syncthreads();
        sm[t] += u;
        __syncthreads();
    }
    if (t < NB) bbase[t] = sm[t] - v;
    if (t == 0) bbase[NB] = E;
}

// ---- scatter: LDS cursors only, packed record src | (dlocal<<26) -----------
__global__ void __launch_bounds__(256)
scatter2_kernel(const int* __restrict__ ei, const int* __restrict__ bbase,
                const int* __restrict__ start2t, unsigned* __restrict__ ebuf,
                int E, int NB, int chunk) {
    __shared__ int hcur[1024];
    const int t = threadIdx.x;
    const int is64 = detect_is64(ei);
    for (int i = t; i < NB; i += 256)
        hcur[i] = bbase[i] + start2t[(long long)i * NBLK + blockIdx.x];
    __syncthreads();
    const int lo = blockIdx.x * chunk;
    const int hi = min(E, lo + chunk);
    for (int e = lo + t; e < hi; e += 256) {
        int s = edge_id(ei, is64, e);
        int d = edge_id(ei, is64, (long long)E + e);
        int pos = atomicAdd(&hcur[d >> BUCK_SH], 1);
        ebuf[pos] = (unsigned)s | ((unsigned)(d & (BUCK - 1)) << 26);
    }
}

// ---- per-bucket exact CSR build: offs, dinv, csr(src only) -----------------
__global__ void __launch_bounds__(256)
csrbuild_kernel(const unsigned* __restrict__ ebuf, const int* __restrict__ bbase,
                int* __restrict__ offs, float* __restrict__ dinv,
                int* __restrict__ csr, int N, int NB, int E) {
    __shared__ int cnt[BUCK], exc[BUCK], cur[BUCK];
    const int b = blockIdx.x;
    const int t = threadIdx.x;
    if (t < BUCK) { cnt[t] = 0; cur[t] = 0; }
    __syncthreads();
    const int lo = bbase[b], hi = bbase[b + 1];
    for (int i = lo + t; i < hi; i += blockDim.x)
        atomicAdd(&cnt[ebuf[i] >> 26], 1);
    __syncthreads();
    if (t == 0) {
        int run = 0;
        for (int l = 0; l < BUCK; ++l) { exc[l] = run; run += cnt[l]; }
    }
    __syncthreads();
    if (t < BUCK) {
        int n = b * BUCK + t;
        if (n < N) {
            offs[n] = lo + exc[t];
            dinv[n] = rsqrtf(1.0f + (float)cnt[t]);
        }
    }
    if (b == NB - 1 && t == 0) offs[N] = E;
    for (int i = lo + t; i < hi; i += blockDim.x) {
        unsigned e = ebuf[i];
        int l = e >> 26;
        int p = lo + exc[l] + atomicAdd(&cur[l], 1);
        csr[p] = (int)(e & 0x03FFFFFFu);
    }
}

// ---------------------------------------------------------------------------
// fp16 MFMA GEMM (GEMM1): C[M,NCOL](fp16) = A[M,K](fp32) @ B[K,NCOL]
// B pre-transposed fp16 [NCOL][K]. BM=128, BK=64, async global_load_lds
// staging, double-buffered, XOR-swizzled 16B units.
// ---------------------------------------------------------------------------
template <int NCOL, int K>
__launch_bounds__(256)
__global__ void gemm_f16_kernel(const float* __restrict__ A,
                                const _Float16* __restrict__ Bt,
                                _Float16* __restrict__ C, int M) {
    constexpr int NCB = NCOL / 16;
    constexpr int BM = 128, BK = 64;
    constexpr int NC = K / BK;
    constexpr int UNITS = BM * BK / 4;
    __shared__ float As[2][BM * BK];

    const int tid  = threadIdx.x;
    const int wave = tid >> 6;
    const int lane = tid & 63;
    const int n15  = lane & 15;
    const int q    = lane >> 4;
    const int row0 = blockIdx.x * BM;

    floatx4 acc[2][NCB];
#pragma unroll
    for (int rt = 0; rt < 2; ++rt)
#pragma unroll
        for (int c = 0; c < NCB; ++c) acc[rt][c] = (floatx4){0.f, 0.f, 0.f, 0.f};

    auto stage = [&](int buf, int kc) {
#pragma unroll
        for (int j = 0; j < UNITS / 256; ++j) {
            int g = j * 256 + tid;
            int r = g >> 4;
            int u = (g & 15) ^ (r & 15);
            int gr = row0 + r;
            if (gr >= M) gr = M - 1;
            const float* gp = &A[(long long)gr * K + kc + u * 4];
            float* lp = &As[buf][g * 4];
            __builtin_amdgcn_global_load_lds(AS1(gp), AS3(lp), 16, 0, 0);
        }
    };

    stage(0, 0);
    __syncthreads();

#pragma unroll
    for (int c = 0; c < NC; ++c) {
        if (c + 1 < NC) stage((c + 1) & 1, (c + 1) * BK);
        const int buf = c & 1;
#pragma unroll
        for (int ks = 0; ks < 2; ++ks) {
            half8v af[2];
#pragma unroll
            for (int rt = 0; rt < 2; ++rt) {
                const int R = wave * 32 + rt * 16 + n15;
                const int u0 = ks * 8 + q * 2;
                const int p0 = (u0)     ^ (R & 15);
                const int p1 = (u0 + 1) ^ (R & 15);
                float4 f0 = *(const float4*)&As[buf][R * BK + p0 * 4];
                float4 f1 = *(const float4*)&As[buf][R * BK + p1 * 4];
                af[rt][0] = (_Float16)f0.x; af[rt][1] = (_Float16)f0.y;
                af[rt][2] = (_Float16)f0.z; af[rt][3] = (_Float16)f0.w;
                af[rt][4] = (_Float16)f1.x; af[rt][5] = (_Float16)f1.y;
                af[rt][6] = (_Float16)f1.z; af[rt][7] = (_Float16)f1.w;
            }
#pragma unroll
            for (int cb = 0; cb < NCB; ++cb) {
                const _Float16* bp = &Bt[(long long)(cb * 16 + n15) * K + c * BK + ks * 32 + q * 8];
                half8v bf = *(const half8v*)bp;
                acc[0][cb] = __builtin_amdgcn_mfma_f32_16x16x32_f16(af[0], bf, acc[0][cb], 0, 0, 0);
                acc[1][cb] = __builtin_amdgcn_mfma_f32_16x16x32_f16(af[1], bf, acc[1][cb], 0, 0, 0);
            }
        }
        if (c + 1 < NC) __syncthreads();
    }

#pragma unroll
    for (int rt = 0; rt < 2; ++rt) {
#pragma unroll
        for (int cb = 0; cb < NCB; ++cb) {
            int col = cb * 16 + n15;
#pragma unroll
            for (int r = 0; r < 4; ++r) {
                int gr = row0 + wave * 32 + rt * 16 + q * 4 + r;
                if (gr < M) C[(long long)gr * NCOL + col] = (_Float16)acc[rt][cb][r];
            }
        }
    }
}

// ---------------------------------------------------------------------------
// Fused gather1 + GEMM2: per block of 16 nodes,
//   agg[16][128] = relu( h1-gather + self-loop + b1 )   (fp32 acc, 16-unroll)
//   -> LDS fp16 (padded) -> per-wave MFMA slice: h2[16][64] = agg @ W2t.
// ---------------------------------------------------------------------------
__global__ void __launch_bounds__(256)
gathergemm_kernel(const _Float16* __restrict__ h, const int* __restrict__ csr,
                  const int* __restrict__ offs, const float* __restrict__ dinv,
                  const float* __restrict__ b1, const _Float16* __restrict__ W2t,
                  _Float16* __restrict__ h2, int N) {
    constexpr int F = 128;
    constexpr int AST = F + 8;            // padded LDS row stride (halves)
    __shared__ _Float16 ah[16 * AST];     // 16 nodes x 128 ch, 2-way-free banks

    const int tid   = threadIdx.x;
    const int local = tid >> 4;           // node in block (0..15)
    const int c8    = (tid & 15) * 8;
    const int n     = blockIdx.x * 16 + local;
    const bool valid = (n < N);

    float acc[8];
    if (valid) {
        const float di = dinv[n];
        half8v hs = *(const half8v*)&h[(long long)n * F + c8];
        const float sd = di * di;
#pragma unroll
        for (int j = 0; j < 8; ++j) acc[j] = (float)hs[j] * sd;

        const int end = offs[n + 1];
        for (int j = offs[n]; j < end; j += 16) {
            int s[16];
            float ws[16];
            half8v v[16];
#pragma unroll
            for (int u = 0; u < 16; ++u) {
                int jj = j + u;
                s[u] = csr[jj < end ? jj : end - 1];
            }
#pragma unroll
            for (int u = 0; u < 16; ++u)
                ws[u] = (j + u < end) ? dinv[s[u]] * di : 0.f;
#pragma unroll
            for (int u = 0; u < 16; ++u) v[u] = *(const half8v*)&h[(long long)s[u] * F + c8];
#pragma unroll
            for (int u = 0; u < 16; ++u) {
#pragma unroll
                for (int t = 0; t < 8; ++t) acc[t] = fmaf((float)v[u][t], ws[u], acc[t]);
            }
        }
        float4 b0 = *(const float4*)&b1[c8];
        float4 bq = *(const float4*)&b1[c8 + 4];
        float bb[8] = {b0.x, b0.y, b0.z, b0.w, bq.x, bq.y, bq.z, bq.w};
#pragma unroll
        for (int t = 0; t < 8; ++t) acc[t] = fmaxf(acc[t] + bb[t], 0.f);
    } else {
#pragma unroll
        for (int t = 0; t < 8; ++t) acc[t] = 0.f;
    }

    // agg tile -> LDS fp16 (A-operand layout source)
    {
        half8v hv;
#pragma unroll
        for (int t = 0; t < 8; ++t) hv[t] = (_Float16)acc[t];
        *(half8v*)&ah[local * AST + c8] = hv;
    }
    __syncthreads();

    // MFMA phase: wave w computes h2 cols [w*16, w*16+16) for the 16 nodes.
    const int wave = tid >> 6;
    const int lane = tid & 63;
    const int n15  = lane & 15;
    const int q    = lane >> 4;
    floatx4 cacc = (floatx4){0.f, 0.f, 0.f, 0.f};
#pragma unroll
    for (int kc = 0; kc < F; kc += 32) {
        half8v af = *(const half8v*)&ah[n15 * AST + kc + q * 8];
        half8v bf = *(const half8v*)&W2t[(long long)(wave * 16 + n15) * F + kc + q * 8];
        cacc = __builtin_amdgcn_mfma_f32_16x16x32_f16(af, bf, cacc, 0, 0, 0);
    }
    // C/D layout: col = lane&15 (+wave*16), row-in-tile = q*4 + r
#pragma unroll
    for (int r = 0; r < 4; ++r) {
        int gr = blockIdx.x * 16 + q * 4 + r;
        if (gr < N) h2[(long long)gr * 64 + wave * 16 + n15] = (_Float16)cacc[r];
    }
}

// ---------------------------------------------------------------------------
// gather2: fp16 h, 8 channels/lane, clamped 8-edge rounds -> out fp32.
// ---------------------------------------------------------------------------
template <int F, int RELU>
__launch_bounds__(256)
__global__ void gatherh_kernel(const _Float16* __restrict__ h, const int* __restrict__ csr,
                               const int* __restrict__ offs, const float* __restrict__ dinv,
                               const float* __restrict__ bias, float* __restrict__ out, int N) {
    constexpr int L = F / 8;
    constexpr int NPB = 256 / L;
    const int n = blockIdx.x * NPB + threadIdx.x / L;
    const int c8 = (threadIdx.x % L) * 8;
    if (n >= N) return;

    const float di = dinv[n];
    half8v hs = *(const half8v*)&h[(long long)n * F + c8];
    float acc[8];
    const float sd = di * di;
#pragma unroll
    for (int j = 0; j < 8; ++j) acc[j] = (float)hs[j] * sd;

    const int end = offs[n + 1];
    for (int j = offs[n]; j < end; j += 8) {
        int s[8];
        float ws[8];
        half8v v[8];
#pragma unroll
        for (int u = 0; u < 8; ++u) {
            int jj = j + u;
            s[u] = csr[jj < end ? jj : end - 1];
        }
#pragma unroll
        for (int u = 0; u < 8; ++u)
            ws[u] = (j + u < end) ? dinv[s[u]] * di : 0.f;
#pragma unroll
        for (int u = 0; u < 8; ++u) v[u] = *(const half8v*)&h[(long long)s[u] * F + c8];
#pragma unroll
        for (int u = 0; u < 8; ++u) {
#pragma unroll
            for (int t = 0; t < 8; ++t) acc[t] = fmaf((float)v[u][t], ws[u], acc[t]);
        }
    }

    float4 b0 = *(const float4*)&bias[c8];
    float4 b1 = *(const float4*)&bias[c8 + 4];
    float bb[8] = {b0.x, b0.y, b0.z, b0.w, b1.x, b1.y, b1.z, b1.w};
#pragma unroll
    for (int t = 0; t < 8; ++t) {
        acc[t] += bb[t];
        if (RELU) acc[t] = fmaxf(acc[t], 0.f);
    }
    float* o = &out[(long long)n * F + c8];
    *(float4*)o       = make_float4(acc[0], acc[1], acc[2], acc[3]);
    *(float4*)(o + 4) = make_float4(acc[4], acc[5], acc[6], acc[7]);
}

extern "C" void kernel_launch(void* const* d_in, const int* in_sizes, int n_in,
                              void* d_out, int out_size, void* d_ws, size_t ws_size,
                              hipStream_t stream) {
    const float* x  = (const float*)d_in[0];
    const int*   ei = (const int*)d_in[1];
    const float* W1 = (const float*)d_in[2];
    const float* b1 = (const float*)d_in[3];
    const float* W2 = (const float*)d_in[4];
    const float* b2 = (const float*)d_in[5];
    float* out = (float*)d_out;

    const int IN_CH = 256, HID = 128, OUT = 64;
    const int N = in_sizes[0] / IN_CH;     // 50000
    const int E = in_sizes[1] / 2;         // 800000
    const int NB = (N + BUCK - 1) / BUCK;  // 782 buckets (< 1024)
    const int chunk = (E + NBLK - 1) / NBLK;

    char* w = (char*)d_ws;
    size_t off_b = 0;
    auto alloc = [&](size_t bytes) { void* p = w + off_b; off_b = (off_b + bytes + 255) & ~(size_t)255; return p; };
    int*   hist2   = (int*)alloc((size_t)NBLK * NB * 4);
    int*   start2t = (int*)alloc((size_t)NB * NBLK * 4);
    int*   colsum  = (int*)alloc((size_t)NB * 4);
    int*   bbase   = (int*)alloc((size_t)(NB + 1) * 4);
    int*   offs    = (int*)alloc((size_t)(N + 1) * 4);
    float* dinv    = (float*)alloc((size_t)N * 4);
    unsigned* ebuf = (unsigned*)alloc((size_t)E * 4);
    int*   csr     = (int*)alloc((size_t)E * 4);
    _Float16* W1t  = (_Float16*)alloc((size_t)IN_CH * HID * 2);
    _Float16* W2t  = (_Float16*)alloc((size_t)HID * OUT * 2);
    _Float16* h1   = (_Float16*)alloc((size_t)N * HID * 2);
    _Float16* h2   = (_Float16*)alloc((size_t)N * OUT * 2);

    // --- preprocessing: 5 dispatches, fully parallel scans -----------------
    hist2convW_kernel<<<NBLK, 256, 0, stream>>>(ei, hist2, E, NB, chunk,
                                                W1, W1t, W2, W2t);
    wavescan_kernel<<<(NB * 64 + 255) / 256, 256, 0, stream>>>(hist2, start2t, colsum, NB);
    basescan_kernel<<<1, 1024, 0, stream>>>(colsum, bbase, NB, E);
    scatter2_kernel<<<NBLK, 256, 0, stream>>>(ei, bbase, start2t, ebuf, E, NB, chunk);
    csrbuild_kernel<<<NB, 256, 0, stream>>>(ebuf, bbase, offs, dinv, csr, N, NB, E);

    // GEMM1: h1[N,128](fp16) = x[N,256] @ W1
    gemm_f16_kernel<128, 256><<<(N + 127) / 128, 256, 0, stream>>>(x, W1t, h1, N);
    // fused layer-1 aggregation + GEMM2 -> h2[N,64] fp16
    gathergemm_kernel<<<(N + 15) / 16, 256, 0, stream>>>(h1, csr, offs, dinv, b1, W2t, h2, N);
    // layer-2 aggregation (fp16 gather, fused self-loop + bias) -> out (fp32)
    gatherh_kernel<64, 0><<<(N * 8 + 255) / 256, 256, 0, stream>>>(h2, csr, offs, dinv, b2, out, N);
}